// Round 2
// baseline (289.748 us; speedup 1.0000x reference)
//
#include <hip/hip_runtime.h>
#include <math.h>

// Problem constants
#define C_DIM 512
#define NHEAD 8
#define HDIM 64
#define NTOK 8000
#define BN_TOK 16000

typedef __attribute__((ext_vector_type(8))) _Float16 f16x8;
typedef __attribute__((ext_vector_type(4))) float f32x4;
typedef __attribute__((ext_vector_type(2))) _Float16 h2;
typedef unsigned short u16;

__device__ __forceinline__ int imin(int a, int b) { return a < b ? a : b; }

// fp32 -> f16 (RNE)
__device__ __forceinline__ u16 f2h(float x) {
    _Float16 h = (_Float16)x;
    return __builtin_bit_cast(u16, h);
}

// async global->LDS, 16 bytes per lane (global_load_lds_dwordx4)
__device__ __forceinline__ void async16(const void* g, void* l) {
    __builtin_amdgcn_global_load_lds(
        (const __attribute__((address_space(1))) void*)g,
        (__attribute__((address_space(3))) void*)l, 16, 0, 0);
}

// ---------------------------------------------------------------------------
// f_kv (B,C,N) fp32 -> kvT (B,N,C) f16. Fixed 512 x 8000 per batch.
// ---------------------------------------------------------------------------
__global__ __launch_bounds__(256) void transpose_c2l_f16(
    const float* __restrict__ in, u16* __restrict__ out)
{
    __shared__ float tile[32][33];
    int b = blockIdx.z;
    const float* inb = in + (size_t)b * 512 * NTOK;
    u16* outb = out + (size_t)b * NTOK * 512;
    int s0 = blockIdx.x * 32, r0 = blockIdx.y * 32;   // s: token, r: channel
    int tx = threadIdx.x & 31, ty = threadIdx.x >> 5;
#pragma unroll
    for (int i = 0; i < 4; i++)
        tile[ty + i * 8][tx] = inb[(size_t)(r0 + ty + i * 8) * NTOK + s0 + tx];
    __syncthreads();
    int rq = threadIdx.x & 7, sy = threadIdx.x >> 3;  // rq: channel quad, sy: token
    ushort4 o;
    o.x = f2h(tile[rq * 4 + 0][sy]);
    o.y = f2h(tile[rq * 4 + 1][sy]);
    o.z = f2h(tile[rq * 4 + 2][sy]);
    o.w = f2h(tile[rq * 4 + 3][sy]);
    *reinterpret_cast<ushort4*>(outb + (size_t)(s0 + sy) * 512 + r0 + rq * 4) = o;
}

// ---------------------------------------------------------------------------
// Merged weight converts: z selects which W (512 x Nout) fp32 -> (Npad x 512)
// f16, pad rows zeroed. Grid (16,16,5); small weights early-out on x.
// ---------------------------------------------------------------------------
__global__ __launch_bounds__(256) void wcvt_all(
    const float* __restrict__ W0, u16* __restrict__ T0,
    const float* __restrict__ W1, u16* __restrict__ T1,
    const float* __restrict__ W2, u16* __restrict__ T2,
    const float* __restrict__ W3, u16* __restrict__ T3,
    const float* __restrict__ W4, u16* __restrict__ T4)
{
    const float* W; u16* Wt; int Nout, Npad;
    switch (blockIdx.z) {
        case 0: W = W0; Wt = T0; Nout = 512; Npad = 512; break;
        case 1: W = W1; Wt = T1; Nout = 512; Npad = 512; break;
        case 2: W = W2; Wt = T2; Nout = 512; Npad = 512; break;
        case 3: W = W3; Wt = T3; Nout = 96;  Npad = 128; break;
        default: W = W4; Wt = T4; Nout = 32; Npad = 128; break;
    }
    int n0 = blockIdx.x * 32, k0 = blockIdx.y * 32;
    if (n0 >= Npad) return;
    __shared__ float t[32][33];
    int tx = threadIdx.x & 31, ty = threadIdx.x >> 5;
#pragma unroll
    for (int i = 0; i < 4; i++) {
        int k = k0 + ty + i * 8, n = n0 + tx;
        t[ty + i * 8][tx] = (n < Nout) ? W[(size_t)k * Nout + n] : 0.f;
    }
    __syncthreads();
#pragma unroll
    for (int i = 0; i < 4; i++) {
        int n = n0 + ty + i * 8, k = k0 + tx;
        Wt[(size_t)n * 512 + k] = f2h(t[tx][ty + i * 8]);
    }
}

// ---------------------------------------------------------------------------
// Fused LayerNorm + (B,C,N)->(B,N,C) transpose, LDS-tiled; f16 output.
// ---------------------------------------------------------------------------
__global__ __launch_bounds__(256) void ln_fused(
    const float* __restrict__ fq, const float* __restrict__ gamma,
    const float* __restrict__ beta, u16* __restrict__ q)
{
    __shared__ float tile[512][33];   // [c][t], 67.6 KB
    __shared__ float ps[32][17], pq[32][17];
    __shared__ float muA[32], rsA[32];
    int blk = blockIdx.x;
    int b = blk / 250;
    int n0 = (blk - b * 250) * 32;
    const float* src = fq + (size_t)b * C_DIM * NTOK + n0;
    int tid = threadIdx.x;
    int cgrp = tid >> 4;          // 0..15
    int tp = (tid & 15) * 2;      // 0,2,..,30
    float s0 = 0.f, q0 = 0.f, s1 = 0.f, q1 = 0.f;
#pragma unroll 4
    for (int it = 0; it < 32; ++it) {
        int c = it * 16 + cgrp;
        float2 v = *reinterpret_cast<const float2*>(src + (size_t)c * NTOK + tp);
        tile[c][tp] = v.x; tile[c][tp + 1] = v.y;
        s0 += v.x; q0 += v.x * v.x;
        s1 += v.y; q1 += v.y * v.y;
    }
    ps[tp][cgrp] = s0; pq[tp][cgrp] = q0;
    ps[tp + 1][cgrp] = s1; pq[tp + 1][cgrp] = q1;
    int lane = tid & 63, wv = tid >> 6;
    float4 g0 = *reinterpret_cast<const float4*>(gamma + lane * 4);
    float4 be0 = *reinterpret_cast<const float4*>(beta + lane * 4);
    float4 g1 = *reinterpret_cast<const float4*>(gamma + 256 + lane * 4);
    float4 be1 = *reinterpret_cast<const float4*>(beta + 256 + lane * 4);
    __syncthreads();
    if (tid < 32) {
        float S = 0.f, SQ = 0.f;
#pragma unroll
        for (int g = 0; g < 16; ++g) { S += ps[tid][g]; SQ += pq[tid][g]; }
        float mu = S * (1.f / 512.f);
        float var = SQ * (1.f / 512.f) - mu * mu;
        muA[tid] = mu;
        rsA[tid] = rsqrtf(var + 1e-5f);
    }
    __syncthreads();
#pragma unroll
    for (int it = 0; it < 16; ++it) {
        int task = it * 4 + wv;     // 0..63 : (token, half)
        int t = task >> 1, h = task & 1;
        int c0 = h * 256 + lane * 4;
        float mu = muA[t], rs = rsA[t];
        float4 g = h ? g1 : g0, bb = h ? be1 : be0;
        ushort4 o;
        o.x = f2h((tile[c0 + 0][t] - mu) * rs * g.x + bb.x);
        o.y = f2h((tile[c0 + 1][t] - mu) * rs * g.y + bb.y);
        o.z = f2h((tile[c0 + 2][t] - mu) * rs * g.z + bb.z);
        o.w = f2h((tile[c0 + 3][t] - mu) * rs * g.w + bb.w);
        *reinterpret_cast<ushort4*>(q + ((size_t)(b * NTOK + n0 + t)) * C_DIM + c0) = o;
    }
}

// ---------------------------------------------------------------------------
// R10: weight-stationary GEMM. K=512 entirely resident: one 64-col weight
// panel (64 x 512 f16 = 64 KB) staged to LDS ONCE (pre-swizzled source ->
// linear LDS, XOR segment swizzle on read; 2-way alias = free, m136), one
// barrier, then a BARRIER-FREE M-loop: A fragments go global->register
// directly (16B contiguous per lane = global_load_dwordx4), B-frags ds_read
// from the resident panel. Waves stream independently -- no collective
// vmcnt(0) drains (R9 post-mortem: those drains were 90% of the 45 us).
// Block = 4 waves, wave-tile 64x32 (acc[4][2]); M-tile 128 rows, 2 tiles
// per block. LDS 64 KB -> 2 blocks/CU; VGPR budget free (8 waves/CU cap).
// outKind 0: fp32 row-major [token*ldc + col]
// outKind 1: f16  row-major [token*512 + col] (+optional relu)
// outKind 2: fp32 transposed (B,C,N): [(b*512+col)*8000 + tok], float4 store
// ---------------------------------------------------------------------------
__device__ __forceinline__ void ws_body(
    const u16* __restrict__ A, const u16* __restrict__ Bp,
    const float* __restrict__ bias, float* __restrict__ Cf,
    u16* __restrict__ Ch, int colBase, int colValid, int ldc,
    int outKind, int relu, int bx)
{
    __shared__ u16 Bs[64 * 512];   // 64 KB
    int tid = threadIdx.x, lane = tid & 63, wv = tid >> 6;

    // stage weight panel: 4096 x 16B chunks, 16 per thread.
    // LDS linear slot (row,seg) <- global k-segment (seg ^ (row&7)).
#pragma unroll
    for (int c = 0; c < 16; c++) {
        int id = c * 256 + tid;
        int row = id >> 6, seg = id & 63;
        async16(Bp + (size_t)row * 512 + ((seg ^ (row & 7)) << 3),
                Bs + (size_t)id * 8);
    }

    int ml = lane & 15, quad = lane >> 4;
    int wm = (wv & 1) * 64, wn = (wv >> 1) * 32;   // 2x2 wave grid over 128x64

    // B-frag read bases: row = wn + j*16 + ml (u16 units)
    int rowj[2];
#pragma unroll
    for (int j = 0; j < 2; j++) rowj[j] = wn + j * 16 + ml;

    __syncthreads();   // panel resident (drains staging vmcnt)

#pragma unroll 1
    for (int mt = bx * 2; mt < bx * 2 + 2; ++mt) {
        if (mt >= 125) break;                       // 125 M-tiles of 128
        int bm = mt * 128;
        const u16* Ap = A + ((size_t)(bm + wm + ml)) * 512 + quad * 8;

        f32x4 acc[4][2];
#pragma unroll
        for (int i = 0; i < 4; i++)
#pragma unroll
            for (int j = 0; j < 2; j++) acc[i][j] = (f32x4){0.f, 0.f, 0.f, 0.f};

#pragma unroll
        for (int kk = 0; kk < 16; kk++) {
            f16x8 af[4], bf[2];
#pragma unroll
            for (int i = 0; i < 4; i++)
                af[i] = *reinterpret_cast<const f16x8*>(
                    Ap + (size_t)i * 16 * 512 + kk * 32);
#pragma unroll
            for (int j = 0; j < 2; j++) {
                int seg = kk * 4 + quad;
                bf[j] = *reinterpret_cast<const f16x8*>(
                    Bs + (size_t)rowj[j] * 512 + ((seg ^ (rowj[j] & 7)) << 3));
            }
#pragma unroll
            for (int i = 0; i < 4; i++)
#pragma unroll
                for (int j = 0; j < 2; j++)
                    acc[i][j] = __builtin_amdgcn_mfma_f32_16x16x32_f16(
                        af[i], bf[j], acc[i][j], 0, 0, 0);
        }

        // epilogue: C/D layout col=lane&15, row=quad*4+reg (m89/m91)
#pragma unroll
        for (int i = 0; i < 4; i++) {
            int row = bm + wm + i * 16 + quad * 4;   // token index (4 consec)
#pragma unroll
            for (int j = 0; j < 2; j++) {
                int col = colBase + wn + j * 16 + ml;
                if (col < colValid) {
                    float bia = bias[col];
                    if (outKind == 2) {
                        int bb = row >= 8000;
                        float4 st;
                        st.x = acc[i][j][0] + bia;
                        st.y = acc[i][j][1] + bia;
                        st.z = acc[i][j][2] + bia;
                        st.w = acc[i][j][3] + bia;
                        *reinterpret_cast<float4*>(
                            Cf + ((size_t)(bb * 512 + col)) * 8000
                               + (row - bb * 8000)) = st;
                    } else if (outKind == 1) {
#pragma unroll
                        for (int rg = 0; rg < 4; rg++) {
                            float v = acc[i][j][rg] + bia;
                            if (relu) v = fmaxf(v, 0.f);
                            Ch[(size_t)(row + rg) * 512 + col] = f2h(v);
                        }
                    } else {
#pragma unroll
                        for (int rg = 0; rg < 4; rg++)
                            Cf[(size_t)(row + rg) * ldc + col] =
                                acc[i][j][rg] + bia;
                    }
                }
            }
        }
    }
}

// 512 flat blocks = 8 panels x 64 M-groups, decoded so the 8 panel-blocks
// sharing one A-slab get the same (did & 7) -> same XCD (A is the 8x-reread
// operand; keep its rereads in one L2). m = 63 decodes to tiles >= 125 ->
// immediate exit (8 spare blocks).
__global__ __launch_bounds__(256) void gemm_ws_big(
    const u16* __restrict__ A, const u16* __restrict__ WT,
    const float* __restrict__ bias, float* __restrict__ Cf,
    u16* __restrict__ Ch, int outKind, int relu)
{
    int did = blockIdx.x;                      // 0..511
    int m = ((did >> 6) << 3) | (did & 7);     // M-group 0..63
    int p = (did >> 3) & 7;                    // panel 0..7
    ws_body(A, WT + (size_t)p * 64 * 512, bias, Cf, Ch,
            p * 64, 512, 512, outKind, relu, m);
}

// dual: y=0 off cols 0..63, y=1 off cols 64..95 (padded panel rows 64..127),
// y=2 logits cols 0..31. Grid (63, 3).
__global__ __launch_bounds__(256) void gemm_ws_dual(
    const u16* __restrict__ hid, const u16* __restrict__ Wo2T,
    const float* __restrict__ bo2, float* __restrict__ offb,
    const u16* __restrict__ Qb, const u16* __restrict__ WaT,
    const float* __restrict__ ba, float* __restrict__ lgb)
{
    int y = blockIdx.y, bx = blockIdx.x;
    const u16* A; const u16* Bp; const float* bias; float* Cf;
    int colBase, colValid, ldc;
    if (y == 0) { A = hid; Bp = Wo2T;            bias = bo2; Cf = offb; colBase = 0;  colValid = 96; ldc = 96; }
    else if (y == 1) { A = hid; Bp = Wo2T + 64 * 512; bias = bo2; Cf = offb; colBase = 64; colValid = 96; ldc = 96; }
    else { A = Qb; Bp = WaT;             bias = ba;  Cf = lgb;  colBase = 0;  colValid = 32; ldc = 32; }
    ws_body(A, Bp, bias, Cf, nullptr, colBase, colValid, ldc, 0, 0, bx);
}

// ---------------------------------------------------------------------------
// Fused softmax + offset clip + trilinear sample + einsum, f16 volume.
// One wave = one token (8 heads); lane = h*8 + cl, 8 channels/lane via one
// uint4 (8 x f16) corner load. Channels accumulate as 4 x h2 via
// v_pk_fma_f16 (2 ch/inst). p-loop NOT unrolled (R6: full unroll -> 132
// VGPR -> 9% occ). 32-bit element offsets.
// XCD swizzle: blockIdx.x & 7 -> 2000-token contiguous slab per XCD.
// Reference quirk: off-ch0 -> W(x) axis, ch1 -> H(y), ch2 -> D(z); H=W=D=20
// collapses normalization to clip(base+off, 0, 19).
// ---------------------------------------------------------------------------
__global__ __launch_bounds__(256) void sample_kernel(
    const u16* __restrict__ vol, const float* __restrict__ offb,
    const float* __restrict__ lgb, u16* __restrict__ outp)
{
    int wid = threadIdx.x >> 6, lane = threadIdx.x & 63;
    int bx = blockIdx.x;                               // 4000 = 8 slabs x 500
    int bn = ((bx & 7) * 500 + (bx >> 3)) * 4 + wid;   // token 0..15999
    int h = lane >> 3, cl = lane & 7;
    int b = bn / NTOK, n = bn - b * NTOK;
    int y = n / 400;
    int r2 = n - y * 400;
    int x = r2 / 20;
    int z = r2 - x * 20;

    const float* op = offb + (size_t)bn * 96 + h * 12;
    const float* lp = lgb + (size_t)bn * 32 + h * 4;
    float l0 = lp[0], l1 = lp[1], l2 = lp[2], l3 = lp[3];
    float mx = fmaxf(fmaxf(l0, l1), fmaxf(l2, l3));
    float e0 = expf(l0 - mx), e1 = expf(l1 - mx), e2 = expf(l2 - mx), e3 = expf(l3 - mx);
    float inv = 1.f / (e0 + e1 + e2 + e3);
    float at[4] = {e0 * inv, e1 * inv, e2 * inv, e3 * inv};

    const u16* volb = vol + b * (NTOK * C_DIM) + h * HDIM + cl * 8;
    h2 acc0 = (h2)(_Float16)0, acc1 = acc0, acc2 = acc0, acc3 = acc0;
#pragma unroll 1
    for (int p = 0; p < 4; p++) {
        float o0 = fminf(fmaxf(op[p * 3 + 0], -3.f), 3.f);
        float o1 = fminf(fmaxf(op[p * 3 + 1], -3.f), 3.f);
        float o2 = fminf(fmaxf(op[p * 3 + 2], -3.f), 3.f);
        float ix = fminf(fmaxf((float)y + o0, 0.f), 19.f);  // W axis
        float iy = fminf(fmaxf((float)x + o1, 0.f), 19.f);  // H axis
        float iz = fminf(fmaxf((float)z + o2, 0.f), 19.f);  // D axis
        float xf = floorf(ix), yf = floorf(iy), zf = floorf(iz);
        float fx = ix - xf, fy = iy - yf, fz = iz - zf;
        int x0 = (int)xf, y0 = (int)yf, z0 = (int)zf;
        int x1 = imin(x0 + 1, 19), y1 = imin(y0 + 1, 19), z1 = imin(z0 + 1, 19);
        // spatial = yi*400 + xi*20 + zi, channels contiguous (stride C_DIM)
        int s00 = y0 * 400 + x0 * 20, s01 = y0 * 400 + x1 * 20;
        int s10 = y1 * 400 + x0 * 20, s11 = y1 * 400 + x1 * 20;
        uint4 v000 = *(const uint4*)(volb + (s00 + z0) * C_DIM);
        uint4 v001 = *(const uint4*)(volb + (s01 + z0) * C_DIM);
        uint4 v010 = *(const uint4*)(volb + (s10 + z0) * C_DIM);
        uint4 v011 = *(const uint4*)(volb + (s11 + z0) * C_DIM);
        uint4 v100 = *(const uint4*)(volb + (s00 + z1) * C_DIM);
        uint4 v101 = *(const uint4*)(volb + (s01 + z1) * C_DIM);
        uint4 v110 = *(const uint4*)(volb + (s10 + z1) * C_DIM);
        uint4 v111 = *(const uint4*)(volb + (s11 + z1) * C_DIM);
        float wz0 = (1.f - fz) * at[p], wz1 = fz * at[p];
        float w00 = wz0 * (1.f - fy), w01 = wz0 * fy;
        float w10 = wz1 * (1.f - fy), w11 = wz1 * fy;
        float gx0 = 1.f - fx;
        float cw[8] = { w00 * gx0, w00 * fx, w01 * gx0, w01 * fx,
                        w10 * gx0, w10 * fx, w11 * gx0, w11 * fx };
        const uint4* cv[8] = { &v000, &v001, &v010, &v011,
                               &v100, &v101, &v110, &v111 };
#pragma unroll
        for (int c = 0; c < 8; c++) {
            _Float16 wh = (_Float16)cw[c];
            h2 w2; w2.x = wh; w2.y = wh;
            uint4 d = *cv[c];
            acc0 += __builtin_bit_cast(h2, d.x) * w2;
            acc1 += __builtin_bit_cast(h2, d.y) * w2;
            acc2 += __builtin_bit_cast(h2, d.z) * w2;
            acc3 += __builtin_bit_cast(h2, d.w) * w2;
        }
    }
    uint4 o;
    o.x = __builtin_bit_cast(unsigned, acc0);
    o.y = __builtin_bit_cast(unsigned, acc1);
    o.z = __builtin_bit_cast(unsigned, acc2);
    o.w = __builtin_bit_cast(unsigned, acc3);
    *reinterpret_cast<uint4*>(outp + (size_t)bn * C_DIM + h * HDIM + cl * 8) = o;
}

// ---------------------------------------------------------------------------
// Launch
// ---------------------------------------------------------------------------
extern "C" void kernel_launch(void* const* d_in, const int* in_sizes, int n_in,
                              void* d_out, int out_size, void* d_ws, size_t ws_size,
                              hipStream_t stream)
{
    const float* f_query = (const float*)d_in[0];
    const float* f_kv    = (const float*)d_in[1];
    const float* ln_g    = (const float*)d_in[2];
    const float* ln_b    = (const float*)d_in[3];
    const float* Wq      = (const float*)d_in[4];
    const float* bq      = (const float*)d_in[5];
    const float* Wo1     = (const float*)d_in[6];
    const float* bo1     = (const float*)d_in[7];
    const float* Wo2     = (const float*)d_in[8];
    const float* bo2     = (const float*)d_in[9];
    const float* Wa      = (const float*)d_in[10];
    const float* ba      = (const float*)d_in[11];
    const float* Wout    = (const float*)d_in[12];
    const float* bout    = (const float*)d_in[13];
    float* out = (float*)d_out;

    float* ws = (float*)d_ws;
    float* offb = ws;                     // 1,536,000 f
    float* lgb  = ws + 1536000;           //   512,000 f
    u16* kvT   = (u16*)(ws + 2048000);    // 16000x512 (f16 channels-last)
    u16* qb    = kvT  + 8192000;          // 16000x512 (q; later sampled)
    u16* Qb    = qb   + 8192000;          // 16000x512
    u16* hid   = Qb   + 8192000;          // 16000x512
    u16* WqT   = hid  + 8192000;          // 512x512
    u16* Wo1T  = WqT + 262144;
    u16* WoutT = Wo1T + 262144;
    u16* Wo2T  = WoutT + 262144;          // 128x512 (96 valid, pad 0)
    u16* WaT   = Wo2T + 65536;            // 128x512 (32 valid, pad 0)
    // total ~75.6 MiB

    dim3 blk(256);
    // all weight transpose-converts in one dispatch (fp32 -> f16 N^T x K)
    wcvt_all<<<dim3(16, 16, 5), blk, 0, stream>>>(
        Wq, WqT, Wo1, Wo1T, Wout, WoutT, Wo2, Wo2T, Wa, WaT);
    // f_kv (B,C,N) fp32 -> kvT (B,N,C) f16
    transpose_c2l_f16<<<dim3(250, 16, 2), blk, 0, stream>>>(f_kv, kvT);
    // q = LN(transpose(f_query)) -> f16, fused LDS tile
    ln_fused<<<dim3(500), blk, 0, stream>>>(f_query, ln_g, ln_b, qb);
    // Q = q @ Wq + bq -> f16
    gemm_ws_big<<<dim3(512), blk, 0, stream>>>(qb, WqT, bq, nullptr, Qb, 1, 0);
    // hidden = relu(Q @ Wo1 + bo1) -> f16
    gemm_ws_big<<<dim3(512), blk, 0, stream>>>(Qb, Wo1T, bo1, nullptr, hid, 1, 1);
    // off = hidden @ Wo2 + bo2 (fp32) AND logits = Q @ Wa + ba (fp32)
    gemm_ws_dual<<<dim3(63, 3), blk, 0, stream>>>(
        hid, Wo2T, bo2, offb, Qb, WaT, ba, lgb);
    // fused sample/softmax/einsum -> qb (f16, raw h2 store)
    sample_kernel<<<dim3(4000), blk, 0, stream>>>(kvT, offb, lgb, qb);
    // out(B,C,N) = (sampled @ Wout + bout)^T : tokens=M, channels=N, float4 st
    gemm_ws_big<<<dim3(512), blk, 0, stream>>>(qb, WoutT, bout, out, nullptr, 2, 0);
}

// Round 3
// 287.082 us; speedup vs baseline: 1.0093x; 1.0093x over previous
//
#include <hip/hip_runtime.h>
#include <math.h>

// Problem constants
#define C_DIM 512
#define NHEAD 8
#define HDIM 64
#define NTOK 8000
#define BN_TOK 16000

typedef __attribute__((ext_vector_type(8))) _Float16 f16x8;
typedef __attribute__((ext_vector_type(4))) float f32x4;
typedef __attribute__((ext_vector_type(2))) _Float16 h2;
typedef unsigned short u16;

__device__ __forceinline__ int imin(int a, int b) { return a < b ? a : b; }

// fp32 -> f16 (RNE)
__device__ __forceinline__ u16 f2h(float x) {
    _Float16 h = (_Float16)x;
    return __builtin_bit_cast(u16, h);
}

// async global->LDS, 16 bytes per lane (global_load_lds_dwordx4)
__device__ __forceinline__ void async16(const void* g, void* l) {
    __builtin_amdgcn_global_load_lds(
        (const __attribute__((address_space(1))) void*)g,
        (__attribute__((address_space(3))) void*)l, 16, 0, 0);
}

// ---------------------------------------------------------------------------
// f_kv (B,C,N) fp32 -> kvT (B,N,C) f16. Fixed 512 x 8000 per batch.
// ---------------------------------------------------------------------------
__global__ __launch_bounds__(256) void transpose_c2l_f16(
    const float* __restrict__ in, u16* __restrict__ out)
{
    __shared__ float tile[32][33];
    int b = blockIdx.z;
    const float* inb = in + (size_t)b * 512 * NTOK;
    u16* outb = out + (size_t)b * NTOK * 512;
    int s0 = blockIdx.x * 32, r0 = blockIdx.y * 32;   // s: token, r: channel
    int tx = threadIdx.x & 31, ty = threadIdx.x >> 5;
#pragma unroll
    for (int i = 0; i < 4; i++)
        tile[ty + i * 8][tx] = inb[(size_t)(r0 + ty + i * 8) * NTOK + s0 + tx];
    __syncthreads();
    int rq = threadIdx.x & 7, sy = threadIdx.x >> 3;  // rq: channel quad, sy: token
    ushort4 o;
    o.x = f2h(tile[rq * 4 + 0][sy]);
    o.y = f2h(tile[rq * 4 + 1][sy]);
    o.z = f2h(tile[rq * 4 + 2][sy]);
    o.w = f2h(tile[rq * 4 + 3][sy]);
    *reinterpret_cast<ushort4*>(outb + (size_t)(s0 + sy) * 512 + r0 + rq * 4) = o;
}

// ---------------------------------------------------------------------------
// Merged weight converts: z selects which W (512 x Nout) fp32 -> (Npad x 512)
// f16, pad rows zeroed. Grid (16,16,5); small weights early-out on x.
// ---------------------------------------------------------------------------
__global__ __launch_bounds__(256) void wcvt_all(
    const float* __restrict__ W0, u16* __restrict__ T0,
    const float* __restrict__ W1, u16* __restrict__ T1,
    const float* __restrict__ W2, u16* __restrict__ T2,
    const float* __restrict__ W3, u16* __restrict__ T3,
    const float* __restrict__ W4, u16* __restrict__ T4)
{
    const float* W; u16* Wt; int Nout, Npad;
    switch (blockIdx.z) {
        case 0: W = W0; Wt = T0; Nout = 512; Npad = 512; break;
        case 1: W = W1; Wt = T1; Nout = 512; Npad = 512; break;
        case 2: W = W2; Wt = T2; Nout = 512; Npad = 512; break;
        case 3: W = W3; Wt = T3; Nout = 96;  Npad = 128; break;
        default: W = W4; Wt = T4; Nout = 32; Npad = 128; break;
    }
    int n0 = blockIdx.x * 32, k0 = blockIdx.y * 32;
    if (n0 >= Npad) return;
    __shared__ float t[32][33];
    int tx = threadIdx.x & 31, ty = threadIdx.x >> 5;
#pragma unroll
    for (int i = 0; i < 4; i++) {
        int k = k0 + ty + i * 8, n = n0 + tx;
        t[ty + i * 8][tx] = (n < Nout) ? W[(size_t)k * Nout + n] : 0.f;
    }
    __syncthreads();
#pragma unroll
    for (int i = 0; i < 4; i++) {
        int n = n0 + ty + i * 8, k = k0 + tx;
        Wt[(size_t)n * 512 + k] = f2h(t[tx][ty + i * 8]);
    }
}

// ---------------------------------------------------------------------------
// Fused LayerNorm + (B,C,N)->(B,N,C) transpose, LDS-tiled; f16 output.
// ---------------------------------------------------------------------------
__global__ __launch_bounds__(256) void ln_fused(
    const float* __restrict__ fq, const float* __restrict__ gamma,
    const float* __restrict__ beta, u16* __restrict__ q)
{
    __shared__ float tile[512][33];   // [c][t], 67.6 KB
    __shared__ float ps[32][17], pq[32][17];
    __shared__ float muA[32], rsA[32];
    int blk = blockIdx.x;
    int b = blk / 250;
    int n0 = (blk - b * 250) * 32;
    const float* src = fq + (size_t)b * C_DIM * NTOK + n0;
    int tid = threadIdx.x;
    int cgrp = tid >> 4;          // 0..15
    int tp = (tid & 15) * 2;      // 0,2,..,30
    float s0 = 0.f, q0 = 0.f, s1 = 0.f, q1 = 0.f;
#pragma unroll 4
    for (int it = 0; it < 32; ++it) {
        int c = it * 16 + cgrp;
        float2 v = *reinterpret_cast<const float2*>(src + (size_t)c * NTOK + tp);
        tile[c][tp] = v.x; tile[c][tp + 1] = v.y;
        s0 += v.x; q0 += v.x * v.x;
        s1 += v.y; q1 += v.y * v.y;
    }
    ps[tp][cgrp] = s0; pq[tp][cgrp] = q0;
    ps[tp + 1][cgrp] = s1; pq[tp + 1][cgrp] = q1;
    int lane = tid & 63, wv = tid >> 6;
    float4 g0 = *reinterpret_cast<const float4*>(gamma + lane * 4);
    float4 be0 = *reinterpret_cast<const float4*>(beta + lane * 4);
    float4 g1 = *reinterpret_cast<const float4*>(gamma + 256 + lane * 4);
    float4 be1 = *reinterpret_cast<const float4*>(beta + 256 + lane * 4);
    __syncthreads();
    if (tid < 32) {
        float S = 0.f, SQ = 0.f;
#pragma unroll
        for (int g = 0; g < 16; ++g) { S += ps[tid][g]; SQ += pq[tid][g]; }
        float mu = S * (1.f / 512.f);
        float var = SQ * (1.f / 512.f) - mu * mu;
        muA[tid] = mu;
        rsA[tid] = rsqrtf(var + 1e-5f);
    }
    __syncthreads();
#pragma unroll
    for (int it = 0; it < 16; ++it) {
        int task = it * 4 + wv;     // 0..63 : (token, half)
        int t = task >> 1, h = task & 1;
        int c0 = h * 256 + lane * 4;
        float mu = muA[t], rs = rsA[t];
        float4 g = h ? g1 : g0, bb = h ? be1 : be0;
        ushort4 o;
        o.x = f2h((tile[c0 + 0][t] - mu) * rs * g.x + bb.x);
        o.y = f2h((tile[c0 + 1][t] - mu) * rs * g.y + bb.y);
        o.z = f2h((tile[c0 + 2][t] - mu) * rs * g.z + bb.z);
        o.w = f2h((tile[c0 + 3][t] - mu) * rs * g.w + bb.w);
        *reinterpret_cast<ushort4*>(q + ((size_t)(b * NTOK + n0 + t)) * C_DIM + c0) = o;
    }
}

// ---------------------------------------------------------------------------
// R11: weight-stationary GEMM, 512-thread blocks (8 waves) for 2x TLP.
// R10 post-mortem: structure OK but 2 blocks/CU x 4 waves = 2 waves/SIMD
// could not hide ~600cyc A-load latency (MfmaUtil 6.9%, Occ 17%). Same 64KB
// panel LDS -> still 2 blocks/CU, but 8-wave blocks -> 16 waves/CU
// (4/SIMD). Wave grid 4Mx2N over a 256x64 block tile; per-wave code
// identical to R10 (barrier-free M-loop, A global->reg, B ds_read from
// resident panel, XOR seg swizzle). __launch_bounds__(512,4) caps VGPR
// at 128 (R10 body measured 116).
// outKind 0: fp32 row-major [token*ldc + col]
// outKind 1: f16  row-major [token*512 + col] (+optional relu)
// outKind 2: fp32 transposed (B,C,N): [(b*512+col)*8000 + tok], float4 store
// ---------------------------------------------------------------------------
__device__ __forceinline__ void ws_body512(
    const u16* __restrict__ A, const u16* __restrict__ Bp,
    const float* __restrict__ bias, float* __restrict__ Cf,
    u16* __restrict__ Ch, int colBase, int colValid, int ldc,
    int outKind, int relu, int mt)
{
    __shared__ u16 Bs[64 * 512];   // 64 KB
    int tid = threadIdx.x, lane = tid & 63, wv = tid >> 6;   // wv 0..7

    // stage weight panel: 4096 x 16B chunks, 8 per thread.
    // LDS linear slot (row,seg) <- global k-segment (seg ^ (row&7)).
#pragma unroll
    for (int c = 0; c < 8; c++) {
        int id = c * 512 + tid;
        int row = id >> 6, seg = id & 63;
        async16(Bp + (size_t)row * 512 + ((seg ^ (row & 7)) << 3),
                Bs + (size_t)id * 8);
    }

    int ml = lane & 15, quad = lane >> 4;
    int wm = (wv >> 1) * 64, wn = (wv & 1) * 32;   // 4x2 wave grid, 256x64

    int rowj[2];
#pragma unroll
    for (int j = 0; j < 2; j++) rowj[j] = wn + j * 16 + ml;

    __syncthreads();   // panel resident (drains staging vmcnt)

    int bm = mt * 256;
    const u16* Ap = A + ((size_t)(bm + wm + ml)) * 512 + quad * 8;

    f32x4 acc[4][2];
#pragma unroll
    for (int i = 0; i < 4; i++)
#pragma unroll
        for (int j = 0; j < 2; j++) acc[i][j] = (f32x4){0.f, 0.f, 0.f, 0.f};

#pragma unroll
    for (int kk = 0; kk < 16; kk++) {
        f16x8 af[4], bf[2];
#pragma unroll
        for (int i = 0; i < 4; i++)
            af[i] = *reinterpret_cast<const f16x8*>(
                Ap + (size_t)i * 16 * 512 + kk * 32);
#pragma unroll
        for (int j = 0; j < 2; j++) {
            int seg = kk * 4 + quad;
            bf[j] = *reinterpret_cast<const f16x8*>(
                Bs + (size_t)rowj[j] * 512 + ((seg ^ (rowj[j] & 7)) << 3));
        }
#pragma unroll
        for (int i = 0; i < 4; i++)
#pragma unroll
            for (int j = 0; j < 2; j++)
                acc[i][j] = __builtin_amdgcn_mfma_f32_16x16x32_f16(
                    af[i], bf[j], acc[i][j], 0, 0, 0);
    }

    // epilogue: C/D layout col=lane&15, row=quad*4+reg (m89/m91)
#pragma unroll
    for (int i = 0; i < 4; i++) {
        int row = bm + wm + i * 16 + quad * 4;   // token index (4 consec)
        if (row >= BN_TOK) continue;             // tail tile (mt=62) guard
#pragma unroll
        for (int j = 0; j < 2; j++) {
            int col = colBase + wn + j * 16 + ml;
            if (col < colValid) {
                float bia = bias[col];
                if (outKind == 2) {
                    int bb = row >= 8000;
                    float4 st;
                    st.x = acc[i][j][0] + bia;
                    st.y = acc[i][j][1] + bia;
                    st.z = acc[i][j][2] + bia;
                    st.w = acc[i][j][3] + bia;
                    *reinterpret_cast<float4*>(
                        Cf + ((size_t)(bb * 512 + col)) * 8000
                           + (row - bb * 8000)) = st;
                } else if (outKind == 1) {
#pragma unroll
                    for (int rg = 0; rg < 4; rg++) {
                        float v = acc[i][j][rg] + bia;
                        if (relu) v = fmaxf(v, 0.f);
                        Ch[(size_t)(row + rg) * 512 + col] = f2h(v);
                    }
                } else {
#pragma unroll
                    for (int rg = 0; rg < 4; rg++)
                        Cf[(size_t)(row + rg) * ldc + col] =
                            acc[i][j][rg] + bia;
                }
            }
        }
    }
}

// 512 flat blocks = 8 panels x 64 M-groups (256 rows each; m=63 -> exit),
// decoded so the 8 panel-blocks sharing one A-slab get the same (did & 7)
// -> same XCD (A is the 8x-reread operand; keep rereads in one L2).
__global__ __launch_bounds__(512, 4) void gemm_ws_big(
    const u16* __restrict__ A, const u16* __restrict__ WT,
    const float* __restrict__ bias, float* __restrict__ Cf,
    u16* __restrict__ Ch, int outKind, int relu)
{
    int did = blockIdx.x;                      // 0..511
    int m = ((did >> 6) << 3) | (did & 7);     // M-group 0..63
    if (m >= 63) return;                       // 63 tiles of 256 cover 16000
    int p = (did >> 3) & 7;                    // panel 0..7
    ws_body512(A, WT + (size_t)p * 64 * 512, bias, Cf, Ch,
               p * 64, 512, 512, outKind, relu, m);
}

// dual: y=0 off cols 0..63, y=1 off cols 64..95 (padded panel rows 64..127),
// y=2 logits cols 0..31. Grid (63, 3).
__global__ __launch_bounds__(512, 4) void gemm_ws_dual(
    const u16* __restrict__ hid, const u16* __restrict__ Wo2T,
    const float* __restrict__ bo2, float* __restrict__ offb,
    const u16* __restrict__ Qb, const u16* __restrict__ WaT,
    const float* __restrict__ ba, float* __restrict__ lgb)
{
    int y = blockIdx.y, mt = blockIdx.x;
    const u16* A; const u16* Bp; const float* bias; float* Cf;
    int colBase, colValid, ldc;
    if (y == 0) { A = hid; Bp = Wo2T;            bias = bo2; Cf = offb; colBase = 0;  colValid = 96; ldc = 96; }
    else if (y == 1) { A = hid; Bp = Wo2T + 64 * 512; bias = bo2; Cf = offb; colBase = 64; colValid = 96; ldc = 96; }
    else { A = Qb; Bp = WaT;             bias = ba;  Cf = lgb;  colBase = 0;  colValid = 32; ldc = 32; }
    ws_body512(A, Bp, bias, Cf, nullptr, colBase, colValid, ldc, 0, 0, mt);
}

// ---------------------------------------------------------------------------
// Fused softmax + offset clip + trilinear sample + einsum, f16 volume.
// One wave = one token (8 heads); lane = h*8 + cl, 8 channels/lane via one
// uint4 (8 x f16) corner load. Channels accumulate as 4 x h2 via
// v_pk_fma_f16 (2 ch/inst). p-loop NOT unrolled (R6: full unroll -> 132
// VGPR -> 9% occ). 32-bit element offsets.
// XCD swizzle: blockIdx.x & 7 -> 2000-token contiguous slab per XCD.
// Reference quirk: off-ch0 -> W(x) axis, ch1 -> H(y), ch2 -> D(z); H=W=D=20
// collapses normalization to clip(base+off, 0, 19).
// ---------------------------------------------------------------------------
__global__ __launch_bounds__(256) void sample_kernel(
    const u16* __restrict__ vol, const float* __restrict__ offb,
    const float* __restrict__ lgb, u16* __restrict__ outp)
{
    int wid = threadIdx.x >> 6, lane = threadIdx.x & 63;
    int bx = blockIdx.x;                               // 4000 = 8 slabs x 500
    int bn = ((bx & 7) * 500 + (bx >> 3)) * 4 + wid;   // token 0..15999
    int h = lane >> 3, cl = lane & 7;
    int b = bn / NTOK, n = bn - b * NTOK;
    int y = n / 400;
    int r2 = n - y * 400;
    int x = r2 / 20;
    int z = r2 - x * 20;

    const float* op = offb + (size_t)bn * 96 + h * 12;
    const float* lp = lgb + (size_t)bn * 32 + h * 4;
    float l0 = lp[0], l1 = lp[1], l2 = lp[2], l3 = lp[3];
    float mx = fmaxf(fmaxf(l0, l1), fmaxf(l2, l3));
    float e0 = expf(l0 - mx), e1 = expf(l1 - mx), e2 = expf(l2 - mx), e3 = expf(l3 - mx);
    float inv = 1.f / (e0 + e1 + e2 + e3);
    float at[4] = {e0 * inv, e1 * inv, e2 * inv, e3 * inv};

    const u16* volb = vol + b * (NTOK * C_DIM) + h * HDIM + cl * 8;
    h2 acc0 = (h2)(_Float16)0, acc1 = acc0, acc2 = acc0, acc3 = acc0;
#pragma unroll 1
    for (int p = 0; p < 4; p++) {
        float o0 = fminf(fmaxf(op[p * 3 + 0], -3.f), 3.f);
        float o1 = fminf(fmaxf(op[p * 3 + 1], -3.f), 3.f);
        float o2 = fminf(fmaxf(op[p * 3 + 2], -3.f), 3.f);
        float ix = fminf(fmaxf((float)y + o0, 0.f), 19.f);  // W axis
        float iy = fminf(fmaxf((float)x + o1, 0.f), 19.f);  // H axis
        float iz = fminf(fmaxf((float)z + o2, 0.f), 19.f);  // D axis
        float xf = floorf(ix), yf = floorf(iy), zf = floorf(iz);
        float fx = ix - xf, fy = iy - yf, fz = iz - zf;
        int x0 = (int)xf, y0 = (int)yf, z0 = (int)zf;
        int x1 = imin(x0 + 1, 19), y1 = imin(y0 + 1, 19), z1 = imin(z0 + 1, 19);
        // spatial = yi*400 + xi*20 + zi, channels contiguous (stride C_DIM)
        int s00 = y0 * 400 + x0 * 20, s01 = y0 * 400 + x1 * 20;
        int s10 = y1 * 400 + x0 * 20, s11 = y1 * 400 + x1 * 20;
        uint4 v000 = *(const uint4*)(volb + (s00 + z0) * C_DIM);
        uint4 v001 = *(const uint4*)(volb + (s01 + z0) * C_DIM);
        uint4 v010 = *(const uint4*)(volb + (s10 + z0) * C_DIM);
        uint4 v011 = *(const uint4*)(volb + (s11 + z0) * C_DIM);
        uint4 v100 = *(const uint4*)(volb + (s00 + z1) * C_DIM);
        uint4 v101 = *(const uint4*)(volb + (s01 + z1) * C_DIM);
        uint4 v110 = *(const uint4*)(volb + (s10 + z1) * C_DIM);
        uint4 v111 = *(const uint4*)(volb + (s11 + z1) * C_DIM);
        float wz0 = (1.f - fz) * at[p], wz1 = fz * at[p];
        float w00 = wz0 * (1.f - fy), w01 = wz0 * fy;
        float w10 = wz1 * (1.f - fy), w11 = wz1 * fy;
        float gx0 = 1.f - fx;
        float cw[8] = { w00 * gx0, w00 * fx, w01 * gx0, w01 * fx,
                        w10 * gx0, w10 * fx, w11 * gx0, w11 * fx };
        const uint4* cv[8] = { &v000, &v001, &v010, &v011,
                               &v100, &v101, &v110, &v111 };
#pragma unroll
        for (int c = 0; c < 8; c++) {
            _Float16 wh = (_Float16)cw[c];
            h2 w2; w2.x = wh; w2.y = wh;
            uint4 d = *cv[c];
            acc0 += __builtin_bit_cast(h2, d.x) * w2;
            acc1 += __builtin_bit_cast(h2, d.y) * w2;
            acc2 += __builtin_bit_cast(h2, d.z) * w2;
            acc3 += __builtin_bit_cast(h2, d.w) * w2;
        }
    }
    uint4 o;
    o.x = __builtin_bit_cast(unsigned, acc0);
    o.y = __builtin_bit_cast(unsigned, acc1);
    o.z = __builtin_bit_cast(unsigned, acc2);
    o.w = __builtin_bit_cast(unsigned, acc3);
    *reinterpret_cast<uint4*>(outp + (size_t)bn * C_DIM + h * HDIM + cl * 8) = o;
}

// ---------------------------------------------------------------------------
// Launch
// ---------------------------------------------------------------------------
extern "C" void kernel_launch(void* const* d_in, const int* in_sizes, int n_in,
                              void* d_out, int out_size, void* d_ws, size_t ws_size,
                              hipStream_t stream)
{
    const float* f_query = (const float*)d_in[0];
    const float* f_kv    = (const float*)d_in[1];
    const float* ln_g    = (const float*)d_in[2];
    const float* ln_b    = (const float*)d_in[3];
    const float* Wq      = (const float*)d_in[4];
    const float* bq      = (const float*)d_in[5];
    const float* Wo1     = (const float*)d_in[6];
    const float* bo1     = (const float*)d_in[7];
    const float* Wo2     = (const float*)d_in[8];
    const float* bo2     = (const float*)d_in[9];
    const float* Wa      = (const float*)d_in[10];
    const float* ba      = (const float*)d_in[11];
    const float* Wout    = (const float*)d_in[12];
    const float* bout    = (const float*)d_in[13];
    float* out = (float*)d_out;

    float* ws = (float*)d_ws;
    float* offb = ws;                     // 1,536,000 f
    float* lgb  = ws + 1536000;           //   512,000 f
    u16* kvT   = (u16*)(ws + 2048000);    // 16000x512 (f16 channels-last)
    u16* qb    = kvT  + 8192000;          // 16000x512 (q; later sampled)
    u16* Qb    = qb   + 8192000;          // 16000x512
    u16* hid   = Qb   + 8192000;          // 16000x512
    u16* WqT   = hid  + 8192000;          // 512x512
    u16* Wo1T  = WqT + 262144;
    u16* WoutT = Wo1T + 262144;
    u16* Wo2T  = WoutT + 262144;          // 128x512 (96 valid, pad 0)
    u16* WaT   = Wo2T + 65536;            // 128x512 (32 valid, pad 0)
    // total ~75.6 MiB

    dim3 blk(256);
    dim3 blk512(512);
    // all weight transpose-converts in one dispatch (fp32 -> f16 N^T x K)
    wcvt_all<<<dim3(16, 16, 5), blk, 0, stream>>>(
        Wq, WqT, Wo1, Wo1T, Wout, WoutT, Wo2, Wo2T, Wa, WaT);
    // f_kv (B,C,N) fp32 -> kvT (B,N,C) f16
    transpose_c2l_f16<<<dim3(250, 16, 2), blk, 0, stream>>>(f_kv, kvT);
    // q = LN(transpose(f_query)) -> f16, fused LDS tile
    ln_fused<<<dim3(500), blk, 0, stream>>>(f_query, ln_g, ln_b, qb);
    // Q = q @ Wq + bq -> f16
    gemm_ws_big<<<dim3(512), blk512, 0, stream>>>(qb, WqT, bq, nullptr, Qb, 1, 0);
    // hidden = relu(Q @ Wo1 + bo1) -> f16
    gemm_ws_big<<<dim3(512), blk512, 0, stream>>>(Qb, Wo1T, bo1, nullptr, hid, 1, 1);
    // off = hidden @ Wo2 + bo2 (fp32) AND logits = Q @ Wa + ba (fp32)
    gemm_ws_dual<<<dim3(63, 3), blk512, 0, stream>>>(
        hid, Wo2T, bo2, offb, Qb, WaT, ba, lgb);
    // fused sample/softmax/einsum -> qb (f16, raw h2 store)
    sample_kernel<<<dim3(4000), blk, 0, stream>>>(kvT, offb, lgb, qb);
    // out(B,C,N) = (sampled @ Wout + bout)^T : tokens=M, channels=N, float4 st
    gemm_ws_big<<<dim3(512), blk512, 0, stream>>>(qb, WoutT, bout, out, nullptr, 2, 0);
}

// Round 4
// 283.872 us; speedup vs baseline: 1.0207x; 1.0113x over previous
//
#include <hip/hip_runtime.h>
#include <math.h>

// Problem constants
#define C_DIM 512
#define NHEAD 8
#define HDIM 64
#define NTOK 8000
#define BN_TOK 16000

typedef __attribute__((ext_vector_type(8))) _Float16 f16x8;
typedef __attribute__((ext_vector_type(4))) float f32x4;
typedef __attribute__((ext_vector_type(2))) _Float16 h2;
typedef unsigned short u16;

__device__ __forceinline__ int imin(int a, int b) { return a < b ? a : b; }

// fp32 -> f16 (RNE)
__device__ __forceinline__ u16 f2h(float x) {
    _Float16 h = (_Float16)x;
    return __builtin_bit_cast(u16, h);
}

// async global->LDS, 16 bytes per lane (global_load_lds_dwordx4)
__device__ __forceinline__ void async16(const void* g, void* l) {
    __builtin_amdgcn_global_load_lds(
        (const __attribute__((address_space(1))) void*)g,
        (__attribute__((address_space(3))) void*)l, 16, 0, 0);
}

// ---------------------------------------------------------------------------
// f_kv (B,C,N) fp32 -> kvT (B,N,C) f16. Fixed 512 x 8000 per batch.
// ---------------------------------------------------------------------------
__global__ __launch_bounds__(256) void transpose_c2l_f16(
    const float* __restrict__ in, u16* __restrict__ out)
{
    __shared__ float tile[32][33];
    int b = blockIdx.z;
    const float* inb = in + (size_t)b * 512 * NTOK;
    u16* outb = out + (size_t)b * NTOK * 512;
    int s0 = blockIdx.x * 32, r0 = blockIdx.y * 32;   // s: token, r: channel
    int tx = threadIdx.x & 31, ty = threadIdx.x >> 5;
#pragma unroll
    for (int i = 0; i < 4; i++)
        tile[ty + i * 8][tx] = inb[(size_t)(r0 + ty + i * 8) * NTOK + s0 + tx];
    __syncthreads();
    int rq = threadIdx.x & 7, sy = threadIdx.x >> 3;  // rq: channel quad, sy: token
    ushort4 o;
    o.x = f2h(tile[rq * 4 + 0][sy]);
    o.y = f2h(tile[rq * 4 + 1][sy]);
    o.z = f2h(tile[rq * 4 + 2][sy]);
    o.w = f2h(tile[rq * 4 + 3][sy]);
    *reinterpret_cast<ushort4*>(outb + (size_t)(s0 + sy) * 512 + r0 + rq * 4) = o;
}

// ---------------------------------------------------------------------------
// Merged weight converts: z selects which W (512 x Nout) fp32 -> (Npad x 512)
// f16, pad rows zeroed. Grid (16,16,5); small weights early-out on x.
// ---------------------------------------------------------------------------
__global__ __launch_bounds__(256) void wcvt_all(
    const float* __restrict__ W0, u16* __restrict__ T0,
    const float* __restrict__ W1, u16* __restrict__ T1,
    const float* __restrict__ W2, u16* __restrict__ T2,
    const float* __restrict__ W3, u16* __restrict__ T3,
    const float* __restrict__ W4, u16* __restrict__ T4)
{
    const float* W; u16* Wt; int Nout, Npad;
    switch (blockIdx.z) {
        case 0: W = W0; Wt = T0; Nout = 512; Npad = 512; break;
        case 1: W = W1; Wt = T1; Nout = 512; Npad = 512; break;
        case 2: W = W2; Wt = T2; Nout = 512; Npad = 512; break;
        case 3: W = W3; Wt = T3; Nout = 96;  Npad = 128; break;
        default: W = W4; Wt = T4; Nout = 32; Npad = 128; break;
    }
    int n0 = blockIdx.x * 32, k0 = blockIdx.y * 32;
    if (n0 >= Npad) return;
    __shared__ float t[32][33];
    int tx = threadIdx.x & 31, ty = threadIdx.x >> 5;
#pragma unroll
    for (int i = 0; i < 4; i++) {
        int k = k0 + ty + i * 8, n = n0 + tx;
        t[ty + i * 8][tx] = (n < Nout) ? W[(size_t)k * Nout + n] : 0.f;
    }
    __syncthreads();
#pragma unroll
    for (int i = 0; i < 4; i++) {
        int n = n0 + ty + i * 8, k = k0 + tx;
        Wt[(size_t)n * 512 + k] = f2h(t[tx][ty + i * 8]);
    }
}

// ---------------------------------------------------------------------------
// Fused LayerNorm + (B,C,N)->(B,N,C) transpose, LDS-tiled; f16 output.
// ---------------------------------------------------------------------------
__global__ __launch_bounds__(256) void ln_fused(
    const float* __restrict__ fq, const float* __restrict__ gamma,
    const float* __restrict__ beta, u16* __restrict__ q)
{
    __shared__ float tile[512][33];   // [c][t], 67.6 KB
    __shared__ float ps[32][17], pq[32][17];
    __shared__ float muA[32], rsA[32];
    int blk = blockIdx.x;
    int b = blk / 250;
    int n0 = (blk - b * 250) * 32;
    const float* src = fq + (size_t)b * C_DIM * NTOK + n0;
    int tid = threadIdx.x;
    int cgrp = tid >> 4;          // 0..15
    int tp = (tid & 15) * 2;      // 0,2,..,30
    float s0 = 0.f, q0 = 0.f, s1 = 0.f, q1 = 0.f;
#pragma unroll 4
    for (int it = 0; it < 32; ++it) {
        int c = it * 16 + cgrp;
        float2 v = *reinterpret_cast<const float2*>(src + (size_t)c * NTOK + tp);
        tile[c][tp] = v.x; tile[c][tp + 1] = v.y;
        s0 += v.x; q0 += v.x * v.x;
        s1 += v.y; q1 += v.y * v.y;
    }
    ps[tp][cgrp] = s0; pq[tp][cgrp] = q0;
    ps[tp + 1][cgrp] = s1; pq[tp + 1][cgrp] = q1;
    int lane = tid & 63, wv = tid >> 6;
    float4 g0 = *reinterpret_cast<const float4*>(gamma + lane * 4);
    float4 be0 = *reinterpret_cast<const float4*>(beta + lane * 4);
    float4 g1 = *reinterpret_cast<const float4*>(gamma + 256 + lane * 4);
    float4 be1 = *reinterpret_cast<const float4*>(beta + 256 + lane * 4);
    __syncthreads();
    if (tid < 32) {
        float S = 0.f, SQ = 0.f;
#pragma unroll
        for (int g = 0; g < 16; ++g) { S += ps[tid][g]; SQ += pq[tid][g]; }
        float mu = S * (1.f / 512.f);
        float var = SQ * (1.f / 512.f) - mu * mu;
        muA[tid] = mu;
        rsA[tid] = rsqrtf(var + 1e-5f);
    }
    __syncthreads();
#pragma unroll
    for (int it = 0; it < 16; ++it) {
        int task = it * 4 + wv;     // 0..63 : (token, half)
        int t = task >> 1, h = task & 1;
        int c0 = h * 256 + lane * 4;
        float mu = muA[t], rs = rsA[t];
        float4 g = h ? g1 : g0, bb = h ? be1 : be0;
        ushort4 o;
        o.x = f2h((tile[c0 + 0][t] - mu) * rs * g.x + bb.x);
        o.y = f2h((tile[c0 + 1][t] - mu) * rs * g.y + bb.y);
        o.z = f2h((tile[c0 + 2][t] - mu) * rs * g.z + bb.z);
        o.w = f2h((tile[c0 + 3][t] - mu) * rs * g.w + bb.w);
        *reinterpret_cast<ushort4*>(q + ((size_t)(b * NTOK + n0 + t)) * C_DIM + c0) = o;
    }
}

// ---------------------------------------------------------------------------
// R12: weight-stationary GEMM + MANUAL SOFTWARE PIPELINE.
// R11 post-mortem: VGPR_Count=52 proved the compiler did ZERO load
// prefetching -- each kk was load->full-latency-wait->8 MFMA (serial ~500cyc
// vs 80cyc compute = 7% MfmaUtil, matching counters). Fix: ring-buffered
// prefetch in source. A-frags 3 iterations ahead (4-deep ring, 64 VGPR);
// B-frags (ds_read) 1 ahead (2-deep ring). All ring indices static after
// full unroll (rule #20). Same 64KB resident panel, barrier-free M-loop,
// 8-wave blocks, XOR seg swizzle, XCD-chunked grid decode.
// outKind 0: fp32 row-major [token*ldc + col]
// outKind 1: f16  row-major [token*512 + col] (+optional relu)
// outKind 2: fp32 transposed (B,C,N): [(b*512+col)*8000 + tok], float4 store
// ---------------------------------------------------------------------------
__device__ __forceinline__ void ws_body512(
    const u16* __restrict__ A, const u16* __restrict__ Bp,
    const float* __restrict__ bias, float* __restrict__ Cf,
    u16* __restrict__ Ch, int colBase, int colValid, int ldc,
    int outKind, int relu, int mt)
{
    __shared__ u16 Bs[64 * 512];   // 64 KB
    int tid = threadIdx.x, lane = tid & 63, wv = tid >> 6;   // wv 0..7

    // stage weight panel: 4096 x 16B chunks, 8 per thread.
    // LDS linear slot (row,seg) <- global k-segment (seg ^ (row&7)).
#pragma unroll
    for (int c = 0; c < 8; c++) {
        int id = c * 512 + tid;
        int row = id >> 6, seg = id & 63;
        async16(Bp + (size_t)row * 512 + ((seg ^ (row & 7)) << 3),
                Bs + (size_t)id * 8);
    }

    int ml = lane & 15, quad = lane >> 4;
    int wm = (wv >> 1) * 64, wn = (wv & 1) * 32;   // 4x2 wave grid, 256x64

    int rowj[2];
#pragma unroll
    for (int j = 0; j < 2; j++) rowj[j] = wn + j * 16 + ml;

    __syncthreads();   // panel resident (drains staging vmcnt)

    int bm = mt * 256;
    const u16* Ap = A + ((size_t)(bm + wm + ml)) * 512 + quad * 8;

    f32x4 acc[4][2];
#pragma unroll
    for (int i = 0; i < 4; i++)
#pragma unroll
        for (int j = 0; j < 2; j++) acc[i][j] = (f32x4){0.f, 0.f, 0.f, 0.f};

    // ring buffers: af 4-deep (prefetch 3 ahead), bf 2-deep (1 ahead)
    f16x8 af[4][4];   // [ring][i]
    f16x8 bf[2][2];   // [ring][j]

#pragma unroll
    for (int kk = 0; kk < 3; kk++)
#pragma unroll
        for (int i = 0; i < 4; i++)
            af[kk][i] = *reinterpret_cast<const f16x8*>(
                Ap + (size_t)i * 16 * 512 + kk * 32);
#pragma unroll
    for (int j = 0; j < 2; j++)
        bf[0][j] = *reinterpret_cast<const f16x8*>(
            Bs + (size_t)rowj[j] * 512 + (((0 + quad) ^ (rowj[j] & 7)) << 3));

#pragma unroll
    for (int kk = 0; kk < 16; kk++) {
        if (kk + 3 < 16) {
#pragma unroll
            for (int i = 0; i < 4; i++)
                af[(kk + 3) & 3][i] = *reinterpret_cast<const f16x8*>(
                    Ap + (size_t)i * 16 * 512 + (kk + 3) * 32);
        }
        if (kk + 1 < 16) {
#pragma unroll
            for (int j = 0; j < 2; j++) {
                int seg = (kk + 1) * 4 + quad;
                bf[(kk + 1) & 1][j] = *reinterpret_cast<const f16x8*>(
                    Bs + (size_t)rowj[j] * 512 + ((seg ^ (rowj[j] & 7)) << 3));
            }
        }
#pragma unroll
        for (int i = 0; i < 4; i++)
#pragma unroll
            for (int j = 0; j < 2; j++)
                acc[i][j] = __builtin_amdgcn_mfma_f32_16x16x32_f16(
                    af[kk & 3][i], bf[kk & 1][j], acc[i][j], 0, 0, 0);
    }

    // epilogue: C/D layout col=lane&15, row=quad*4+reg (m89/m91)
#pragma unroll
    for (int i = 0; i < 4; i++) {
        int row = bm + wm + i * 16 + quad * 4;   // token index (4 consec)
        if (row >= BN_TOK) continue;             // tail tile (mt=62) guard
#pragma unroll
        for (int j = 0; j < 2; j++) {
            int col = colBase + wn + j * 16 + ml;
            if (col < colValid) {
                float bia = bias[col];
                if (outKind == 2) {
                    int bb = row >= 8000;
                    float4 st;
                    st.x = acc[i][j][0] + bia;
                    st.y = acc[i][j][1] + bia;
                    st.z = acc[i][j][2] + bia;
                    st.w = acc[i][j][3] + bia;
                    *reinterpret_cast<float4*>(
                        Cf + ((size_t)(bb * 512 + col)) * 8000
                           + (row - bb * 8000)) = st;
                } else if (outKind == 1) {
#pragma unroll
                    for (int rg = 0; rg < 4; rg++) {
                        float v = acc[i][j][rg] + bia;
                        if (relu) v = fmaxf(v, 0.f);
                        Ch[(size_t)(row + rg) * 512 + col] = f2h(v);
                    }
                } else {
#pragma unroll
                    for (int rg = 0; rg < 4; rg++)
                        Cf[(size_t)(row + rg) * ldc + col] =
                            acc[i][j][rg] + bia;
                }
            }
        }
    }
}

// 512 flat blocks = 8 panels x 64 M-groups (256 rows each; m=63 -> exit),
// decoded so the 8 panel-blocks sharing one A-slab get the same (did & 7)
// -> same XCD (A is the 8x-reread operand; keep rereads in one L2).
__global__ __launch_bounds__(512, 4) void gemm_ws_big(
    const u16* __restrict__ A, const u16* __restrict__ WT,
    const float* __restrict__ bias, float* __restrict__ Cf,
    u16* __restrict__ Ch, int outKind, int relu)
{
    int did = blockIdx.x;                      // 0..511
    int m = ((did >> 6) << 3) | (did & 7);     // M-group 0..63
    if (m >= 63) return;                       // 63 tiles of 256 cover 16000
    int p = (did >> 3) & 7;                    // panel 0..7
    ws_body512(A, WT + (size_t)p * 64 * 512, bias, Cf, Ch,
               p * 64, 512, 512, outKind, relu, m);
}

// dual: y=0 off cols 0..63, y=1 off cols 64..95 (padded panel rows 64..127),
// y=2 logits cols 0..31. Grid (63, 3).
__global__ __launch_bounds__(512, 4) void gemm_ws_dual(
    const u16* __restrict__ hid, const u16* __restrict__ Wo2T,
    const float* __restrict__ bo2, float* __restrict__ offb,
    const u16* __restrict__ Qb, const u16* __restrict__ WaT,
    const float* __restrict__ ba, float* __restrict__ lgb)
{
    int y = blockIdx.y, mt = blockIdx.x;
    const u16* A; const u16* Bp; const float* bias; float* Cf;
    int colBase, colValid, ldc;
    if (y == 0) { A = hid; Bp = Wo2T;            bias = bo2; Cf = offb; colBase = 0;  colValid = 96; ldc = 96; }
    else if (y == 1) { A = hid; Bp = Wo2T + 64 * 512; bias = bo2; Cf = offb; colBase = 64; colValid = 96; ldc = 96; }
    else { A = Qb; Bp = WaT;             bias = ba;  Cf = lgb;  colBase = 0;  colValid = 32; ldc = 32; }
    ws_body512(A, Bp, bias, Cf, nullptr, colBase, colValid, ldc, 0, 0, mt);
}

// ---------------------------------------------------------------------------
// Fused softmax + offset clip + trilinear sample + einsum, f16 volume.
// One wave = one token (8 heads); lane = h*8 + cl, 8 channels/lane via one
// uint4 (8 x f16) corner load. Channels accumulate as 4 x h2 via
// v_pk_fma_f16 (2 ch/inst). p-loop NOT unrolled (R6: full unroll -> 132
// VGPR -> 9% occ). 32-bit element offsets.
// XCD swizzle: blockIdx.x & 7 -> 2000-token contiguous slab per XCD.
// Reference quirk: off-ch0 -> W(x) axis, ch1 -> H(y), ch2 -> D(z); H=W=D=20
// collapses normalization to clip(base+off, 0, 19).
// ---------------------------------------------------------------------------
__global__ __launch_bounds__(256) void sample_kernel(
    const u16* __restrict__ vol, const float* __restrict__ offb,
    const float* __restrict__ lgb, u16* __restrict__ outp)
{
    int wid = threadIdx.x >> 6, lane = threadIdx.x & 63;
    int bx = blockIdx.x;                               // 4000 = 8 slabs x 500
    int bn = ((bx & 7) * 500 + (bx >> 3)) * 4 + wid;   // token 0..15999
    int h = lane >> 3, cl = lane & 7;
    int b = bn / NTOK, n = bn - b * NTOK;
    int y = n / 400;
    int r2 = n - y * 400;
    int x = r2 / 20;
    int z = r2 - x * 20;

    const float* op = offb + (size_t)bn * 96 + h * 12;
    const float* lp = lgb + (size_t)bn * 32 + h * 4;
    float l0 = lp[0], l1 = lp[1], l2 = lp[2], l3 = lp[3];
    float mx = fmaxf(fmaxf(l0, l1), fmaxf(l2, l3));
    float e0 = expf(l0 - mx), e1 = expf(l1 - mx), e2 = expf(l2 - mx), e3 = expf(l3 - mx);
    float inv = 1.f / (e0 + e1 + e2 + e3);
    float at[4] = {e0 * inv, e1 * inv, e2 * inv, e3 * inv};

    const u16* volb = vol + b * (NTOK * C_DIM) + h * HDIM + cl * 8;
    h2 acc0 = (h2)(_Float16)0, acc1 = acc0, acc2 = acc0, acc3 = acc0;
#pragma unroll 1
    for (int p = 0; p < 4; p++) {
        float o0 = fminf(fmaxf(op[p * 3 + 0], -3.f), 3.f);
        float o1 = fminf(fmaxf(op[p * 3 + 1], -3.f), 3.f);
        float o2 = fminf(fmaxf(op[p * 3 + 2], -3.f), 3.f);
        float ix = fminf(fmaxf((float)y + o0, 0.f), 19.f);  // W axis
        float iy = fminf(fmaxf((float)x + o1, 0.f), 19.f);  // H axis
        float iz = fminf(fmaxf((float)z + o2, 0.f), 19.f);  // D axis
        float xf = floorf(ix), yf = floorf(iy), zf = floorf(iz);
        float fx = ix - xf, fy = iy - yf, fz = iz - zf;
        int x0 = (int)xf, y0 = (int)yf, z0 = (int)zf;
        int x1 = imin(x0 + 1, 19), y1 = imin(y0 + 1, 19), z1 = imin(z0 + 1, 19);
        // spatial = yi*400 + xi*20 + zi, channels contiguous (stride C_DIM)
        int s00 = y0 * 400 + x0 * 20, s01 = y0 * 400 + x1 * 20;
        int s10 = y1 * 400 + x0 * 20, s11 = y1 * 400 + x1 * 20;
        uint4 v000 = *(const uint4*)(volb + (s00 + z0) * C_DIM);
        uint4 v001 = *(const uint4*)(volb + (s01 + z0) * C_DIM);
        uint4 v010 = *(const uint4*)(volb + (s10 + z0) * C_DIM);
        uint4 v011 = *(const uint4*)(volb + (s11 + z0) * C_DIM);
        uint4 v100 = *(const uint4*)(volb + (s00 + z1) * C_DIM);
        uint4 v101 = *(const uint4*)(volb + (s01 + z1) * C_DIM);
        uint4 v110 = *(const uint4*)(volb + (s10 + z1) * C_DIM);
        uint4 v111 = *(const uint4*)(volb + (s11 + z1) * C_DIM);
        float wz0 = (1.f - fz) * at[p], wz1 = fz * at[p];
        float w00 = wz0 * (1.f - fy), w01 = wz0 * fy;
        float w10 = wz1 * (1.f - fy), w11 = wz1 * fy;
        float gx0 = 1.f - fx;
        float cw[8] = { w00 * gx0, w00 * fx, w01 * gx0, w01 * fx,
                        w10 * gx0, w10 * fx, w11 * gx0, w11 * fx };
        const uint4* cv[8] = { &v000, &v001, &v010, &v011,
                               &v100, &v101, &v110, &v111 };
#pragma unroll
        for (int c = 0; c < 8; c++) {
            _Float16 wh = (_Float16)cw[c];
            h2 w2; w2.x = wh; w2.y = wh;
            uint4 d = *cv[c];
            acc0 += __builtin_bit_cast(h2, d.x) * w2;
            acc1 += __builtin_bit_cast(h2, d.y) * w2;
            acc2 += __builtin_bit_cast(h2, d.z) * w2;
            acc3 += __builtin_bit_cast(h2, d.w) * w2;
        }
    }
    uint4 o;
    o.x = __builtin_bit_cast(unsigned, acc0);
    o.y = __builtin_bit_cast(unsigned, acc1);
    o.z = __builtin_bit_cast(unsigned, acc2);
    o.w = __builtin_bit_cast(unsigned, acc3);
    *reinterpret_cast<uint4*>(outp + (size_t)bn * C_DIM + h * HDIM + cl * 8) = o;
}

// ---------------------------------------------------------------------------
// Launch
// ---------------------------------------------------------------------------
extern "C" void kernel_launch(void* const* d_in, const int* in_sizes, int n_in,
                              void* d_out, int out_size, void* d_ws, size_t ws_size,
                              hipStream_t stream)
{
    const float* f_query = (const float*)d_in[0];
    const float* f_kv    = (const float*)d_in[1];
    const float* ln_g    = (const float*)d_in[2];
    const float* ln_b    = (const float*)d_in[3];
    const float* Wq      = (const float*)d_in[4];
    const float* bq      = (const float*)d_in[5];
    const float* Wo1     = (const float*)d_in[6];
    const float* bo1     = (const float*)d_in[7];
    const float* Wo2     = (const float*)d_in[8];
    const float* bo2     = (const float*)d_in[9];
    const float* Wa      = (const float*)d_in[10];
    const float* ba      = (const float*)d_in[11];
    const float* Wout    = (const float*)d_in[12];
    const float* bout    = (const float*)d_in[13];
    float* out = (float*)d_out;

    float* ws = (float*)d_ws;
    float* offb = ws;                     // 1,536,000 f
    float* lgb  = ws + 1536000;           //   512,000 f
    u16* kvT   = (u16*)(ws + 2048000);    // 16000x512 (f16 channels-last)
    u16* qb    = kvT  + 8192000;          // 16000x512 (q; later sampled)
    u16* Qb    = qb   + 8192000;          // 16000x512
    u16* hid   = Qb   + 8192000;          // 16000x512
    u16* WqT   = hid  + 8192000;          // 512x512
    u16* Wo1T  = WqT + 262144;
    u16* WoutT = Wo1T + 262144;
    u16* Wo2T  = WoutT + 262144;          // 128x512 (96 valid, pad 0)
    u16* WaT   = Wo2T + 65536;            // 128x512 (32 valid, pad 0)
    // total ~75.6 MiB

    dim3 blk(256);
    dim3 blk512(512);
    // all weight transpose-converts in one dispatch (fp32 -> f16 N^T x K)
    wcvt_all<<<dim3(16, 16, 5), blk, 0, stream>>>(
        Wq, WqT, Wo1, Wo1T, Wout, WoutT, Wo2, Wo2T, Wa, WaT);
    // f_kv (B,C,N) fp32 -> kvT (B,N,C) f16
    transpose_c2l_f16<<<dim3(250, 16, 2), blk, 0, stream>>>(f_kv, kvT);
    // q = LN(transpose(f_query)) -> f16, fused LDS tile
    ln_fused<<<dim3(500), blk, 0, stream>>>(f_query, ln_g, ln_b, qb);
    // Q = q @ Wq + bq -> f16
    gemm_ws_big<<<dim3(512), blk512, 0, stream>>>(qb, WqT, bq, nullptr, Qb, 1, 0);
    // hidden = relu(Q @ Wo1 + bo1) -> f16
    gemm_ws_big<<<dim3(512), blk512, 0, stream>>>(Qb, Wo1T, bo1, nullptr, hid, 1, 1);
    // off = hidden @ Wo2 + bo2 (fp32) AND logits = Q @ Wa + ba (fp32)
    gemm_ws_dual<<<dim3(63, 3), blk512, 0, stream>>>(
        hid, Wo2T, bo2, offb, Qb, WaT, ba, lgb);
    // fused sample/softmax/einsum -> qb (f16, raw h2 store)
    sample_kernel<<<dim3(4000), blk, 0, stream>>>(kvT, offb, lgb, qb);
    // out(B,C,N) = (sampled @ Wout + bout)^T : tokens=M, channels=N, float4 st
    gemm_ws_big<<<dim3(512), blk512, 0, stream>>>(qb, WoutT, bout, out, nullptr, 2, 0);
}